// Round 2
// baseline (226.636 us; speedup 1.0000x reference)
//
#include <hip/hip_runtime.h>
#include <hip/hip_bf16.h>

// ---------------------------------------------------------------------------
// Fused: h = rmsnorm(x@W0+b0); h = sigmoid(h@W1+b1)+h; out = relu(h@W2+b2)+h
// M=32768, D=1024, H=128.  fp32 in / fp32 out, bf16 MFMA with fp32 accum.
//
// R9: TLP + decoupling fix (fused est ~61us; total still ~155us harness
// poison fills we cannot touch):
//  - M-tile 32, 256 threads (4 waves), grid 1024 = 4 blocks/CU (was 2).
//    Twice the independent barrier groups per CU for latency hiding.
//  - W0 no longer staged through LDS: each wave's B-rows are private to it,
//    and W0T (256KB) is L2-resident. b-fragments load straight from global
//    into registers, depth-2 slab prefetch. Same logical values as the old
//    LDS path -> bit-identical MFMA operand sequence.
//  - LDS 49KB -> 24KB (x-slab dbuf 8KB + hns/h1s 16KB).
//  Numerics identical to R8 (same K order, rounding, swizzles).
// ---------------------------------------------------------------------------

using u16    = unsigned short;
using f32x4  = __attribute__((ext_vector_type(4))) float;
using bf16x8 = __attribute__((ext_vector_type(8))) short;   // 8 bf16 = 4 VGPRs
using u16x8  = __attribute__((ext_vector_type(8))) unsigned short;

__device__ __forceinline__ float bf2f(u16 u) {
  union { unsigned int i; float f; } v; v.i = ((unsigned int)u) << 16; return v.f;
}
__device__ __forceinline__ u16 f2bf(float f) {
  union { float f; unsigned int i; } v; v.f = f;
  unsigned int r = v.i + 0x7fffu + ((v.i >> 16) & 1u);   // RNE
  return (u16)(r >> 16);
}

// ws layout (byte offsets): [0,64) unused; W0T bf16[128][1024] @64;
// W1T bf16[128][128] @262208; W2T @294976; biases fp32[3][128] @327744.
#define WS_W0T 64
#define WS_W1T 262208
#define WS_W2T 294976
#define WS_BIAS 327744

// swizzled byte offset into [rows][16 chunks of 8 bf16] tile (256B/row)
__device__ __forceinline__ int hoff(int row, int col) {
  return row * 256 + (((col >> 3) ^ (row & 7)) << 4) + ((col & 7) << 1);
}

// ---------------------------------------------------------------------------
// prep: W0(1024x128) fp32 -> W0T bf16; W1/W2(128x128) fp32 -> W1T/W2T bf16;
// biases fp32 -> fp32. blocks 0..127 W0, 128..143 W1, 144..159 W2, 160 biases.
// (unchanged)
// ---------------------------------------------------------------------------
__global__ void __launch_bounds__(256)
prep_kernel(const float* __restrict__ W0, const float* __restrict__ W1,
            const float* __restrict__ W2, const float* __restrict__ b0,
            const float* __restrict__ b1, const float* __restrict__ b2,
            char* __restrict__ wsb) {
  const int bid = blockIdx.x;
  if (bid == 160) {
    float* bias = (float*)(wsb + WS_BIAS);
    for (int i = threadIdx.x; i < 384; i += 256) {
      int which = i >> 7, j = i & 127;
      const float* src = (which == 0) ? b0 : (which == 1) ? b1 : b2;
      bias[i] = src[j];
    }
    return;
  }
  __shared__ float tile[32][33];
  const float* src; u16* dst; int K, N, kt, nt;
  if (bid < 128)      { src = W0; dst = (u16*)(wsb + WS_W0T); K = 1024; N = 128; kt = bid >> 2;         nt = bid & 3; }
  else if (bid < 144) { src = W1; dst = (u16*)(wsb + WS_W1T); K = 128;  N = 128; kt = (bid - 128) >> 2; nt = (bid - 128) & 3; }
  else                { src = W2; dst = (u16*)(wsb + WS_W2T); K = 128;  N = 128; kt = (bid - 144) >> 2; nt = (bid - 144) & 3; }
  const int tx = threadIdx.x & 31, ty = threadIdx.x >> 5;
#pragma unroll
  for (int i = 0; i < 4; ++i) {
    int k = kt * 32 + ty + i * 8, n = nt * 32 + tx;
    tile[ty + i * 8][tx] = src[(size_t)k * N + n];
  }
  __syncthreads();
#pragma unroll
  for (int i = 0; i < 4; ++i) {
    int n = nt * 32 + ty + i * 8, k = kt * 32 + tx;
    dst[(size_t)n * K + k] = f2bf(tile[tx][ty + i * 8]);
  }
}

// ---------------------------------------------------------------------------
// fused kernel — M-tile 32, 256 threads (4 waves, n_base = wave*32),
// grid 1024 (4 blocks/CU). x reg-prefetch depth-2 -> bf16 LDS dbuf;
// W0 b-fragments direct from global (L2-resident), depth-2 reg prefetch.
// LDS: bufA_x@0 (4K), bufB_x@4096 (4K), hns@8192 (8K), h1s@16384 (8K).
// ---------------------------------------------------------------------------
__global__ void __launch_bounds__(256, 4)
fused_kernel(const float* __restrict__ xin, const char* __restrict__ wsb,
             float* __restrict__ outv) {
  __shared__ char smem[24576];
  char* bufA = smem;            // x slab A, [32r][8 chunks]*16B = 4KB
  char* bufB = smem + 4096;     // x slab B, 4KB
  char* hns  = smem + 8192;     // [32][128] bf16 swizzled, 8KB
  char* h1s  = smem + 16384;    // 8KB

  const u16* w0t    = (const u16*)(wsb + WS_W0T);
  const u16* w1t    = (const u16*)(wsb + WS_W1T);
  const u16* w2t    = (const u16*)(wsb + WS_W2T);
  const float* bias = (const float*)(wsb + WS_BIAS);

  const int tid    = threadIdx.x;
  const int lane   = tid & 63;
  const int wave   = tid >> 6;
  const int lane16 = lane & 15;
  const int quad   = lane >> 4;
  const int n_base = wave * 32;           // 4 N-waves cover 128 cols
  const int row0   = blockIdx.x * 32;

  // x staging: 32 rows x 8 chunks(16B bf16) = 256 chunks -> 1/thread
  const int rx  = tid >> 3;               // 0..31
  const int cx  = tid & 7;
  const int xsw = ((cx ^ (rx & 7)) << 4); // swizzled chunk offset

  // depth-2 prefetch: raw fp32 x (convert at LDS-write time) + direct b-frags
  f32x4 xA0, xA1, xB0, xB1;
  bf16x8 bA[2][2], bB[2][2];              // [kk][nt], static-indexed

  auto preload_x = [&](f32x4& x0, f32x4& x1, int k0) {
    const float* p = xin + (size_t)(row0 + rx) * 1024 + k0 + cx * 8;
    x0 = *(const f32x4*)p;
    x1 = *(const f32x4*)(p + 4);
  };
  auto preload_b = [&](bf16x8 (&bfr)[2][2], int k0) {
#pragma unroll
    for (int kk = 0; kk < 2; ++kk)
#pragma unroll
      for (int nt = 0; nt < 2; ++nt)
        bfr[kk][nt] = *(const bf16x8*)(
            w0t + (size_t)(n_base + nt * 16 + lane16) * 1024 + k0 +
            (kk * 4 + quad) * 8);
  };
  auto stage_x = [&](char* xs, const f32x4& x0, const f32x4& x1) {
    u16x8 t;
#pragma unroll
    for (int e = 0; e < 4; ++e) { t[e] = f2bf(x0[e]); t[e + 4] = f2bf(x1[e]); }
    *(u16x8*)(xs + rx * 128 + xsw) = t;
  };

  f32x4 acc[2][2] = {};

  auto mmac = [&](const char* xs, bf16x8 (&bfr)[2][2]) {
#pragma unroll
    for (int kk = 0; kk < 2; ++kk) {
      int ph = ((kk * 4 + quad) ^ (lane & 7)) << 4;
      bf16x8 a[2];
#pragma unroll
      for (int rh = 0; rh < 2; ++rh)
        a[rh] = *(const bf16x8*)(xs + (rh * 16 + lane16) * 128 + ph);
#pragma unroll
      for (int rh = 0; rh < 2; ++rh)
#pragma unroll
        for (int nt = 0; nt < 2; ++nt)
          acc[rh][nt] = __builtin_amdgcn_mfma_f32_16x16x32_bf16(
              a[rh], bfr[kk][nt], acc[rh][nt], 0, 0, 0);
    }
  };

  float b0v[2];
#pragma unroll
  for (int nt = 0; nt < 2; ++nt) b0v[nt] = bias[n_base + nt * 16 + lane16];

  preload_x(xA0, xA1, 0);  preload_b(bA, 0);
  preload_x(xB0, xB1, 64); preload_b(bB, 64);

  // ---- GEMM0: h = x @ W0, K=1024, 16 slabs of BK=64, double-buffered.
  // One barrier per slab. WAR on buf[s&1]: last read at slab s-2, the
  // barrier at slab s-1 intervenes. b-regs reload only after consumption.
  for (int ss = 0; ss < 8; ++ss) {
    const int s0 = ss * 2;
    stage_x(bufA, xA0, xA1);
    if (s0 + 2 < 16) preload_x(xA0, xA1, (s0 + 2) * 64);
    __syncthreads();
    mmac(bufA, bA);
    if (s0 + 2 < 16) preload_b(bA, (s0 + 2) * 64);

    stage_x(bufB, xB0, xB1);
    if (s0 + 3 < 16) preload_x(xB0, xB1, (s0 + 3) * 64);
    __syncthreads();
    mmac(bufB, bB);
    if (s0 + 3 < 16) preload_b(bB, (s0 + 3) * 64);
  }
  // no barrier needed: scatter targets hns@[8K,16K); stragglers of the last
  // slab only read bufB@[4K,8K) (disjoint).

  // ---- scatter h+b0 -> hns (C-layout: col=lane16, row=quad*4+reg) ----
#pragma unroll
  for (int rh = 0; rh < 2; ++rh)
#pragma unroll
    for (int nt = 0; nt < 2; ++nt) {
      int col = n_base + nt * 16 + lane16;
#pragma unroll
      for (int r = 0; r < 4; ++r) {
        int row = rh * 16 + quad * 4 + r;
        *(u16*)(hns + hoff(row, col)) = f2bf(acc[rh][nt][r] + b0v[nt]);
      }
    }
  __syncthreads();

  // ---- rmsnorm over H=128: 8 threads/row, 2 chunks each (32 rows) ----
  {
    int r = tid >> 3, q = tid & 7;
    u16x8 vals[2];
    float sum = 0.f;
#pragma unroll
    for (int j = 0; j < 2; ++j) {
      int c = q * 2 + j;
      vals[j] = *(const u16x8*)(hns + r * 256 + ((c ^ (r & 7)) << 4));
#pragma unroll
      for (int e = 0; e < 8; ++e) { float f = bf2f(vals[j][e]); sum += f * f; }
    }
    sum += __shfl_xor(sum, 1);
    sum += __shfl_xor(sum, 2);
    sum += __shfl_xor(sum, 4);
    float scale = rsqrtf(sum * (1.f / 128.f) + 1e-6f);
#pragma unroll
    for (int j = 0; j < 2; ++j) {
      u16x8 o;
#pragma unroll
      for (int e = 0; e < 8; ++e) o[e] = f2bf(bf2f(vals[j][e]) * scale);
      int c = q * 2 + j;
      *(u16x8*)(hns + r * 256 + ((c ^ (r & 7)) << 4)) = o;
    }
  }
  __syncthreads();

  // ---- GEMM1: h1 = sigmoid(hn @ W1 + b1) + hn -> h1s ----
  float b1v[2];
#pragma unroll
  for (int nt = 0; nt < 2; ++nt) b1v[nt] = bias[128 + n_base + nt * 16 + lane16];
  f32x4 acc1[2][2] = {};
#pragma unroll
  for (int kk = 0; kk < 4; ++kk) {
    int ph = ((kk * 4 + quad) ^ (lane & 7)) << 4;
    bf16x8 a[2], b[2];
#pragma unroll
    for (int rh = 0; rh < 2; ++rh)
      a[rh] = *(const bf16x8*)(hns + (rh * 16 + lane16) * 256 + ph);
#pragma unroll
    for (int nt = 0; nt < 2; ++nt)
      b[nt] = *(const bf16x8*)(w1t + (size_t)(n_base + nt * 16 + lane16) * 128 +
                               kk * 32 + quad * 8);
#pragma unroll
    for (int rh = 0; rh < 2; ++rh)
#pragma unroll
      for (int nt = 0; nt < 2; ++nt)
        acc1[rh][nt] = __builtin_amdgcn_mfma_f32_16x16x32_bf16(
            a[rh], b[nt], acc1[rh][nt], 0, 0, 0);
  }
#pragma unroll
  for (int rh = 0; rh < 2; ++rh)
#pragma unroll
    for (int nt = 0; nt < 2; ++nt) {
      int col = n_base + nt * 16 + lane16;
#pragma unroll
      for (int r = 0; r < 4; ++r) {
        int row = rh * 16 + quad * 4 + r;
        int o = hoff(row, col);
        float hn = bf2f(*(const u16*)(hns + o));
        float v = acc1[rh][nt][r] + b1v[nt];
        *(u16*)(h1s + o) = f2bf(hn + 1.f / (1.f + __expf(-v)));
      }
    }
  __syncthreads();

  // ---- GEMM2: out = relu(h1 @ W2 + b2) + h1, fused fp32 store ----
  float b2v[2];
#pragma unroll
  for (int nt = 0; nt < 2; ++nt) b2v[nt] = bias[256 + n_base + nt * 16 + lane16];
  f32x4 acc2[2][2] = {};
#pragma unroll
  for (int kk = 0; kk < 4; ++kk) {
    int ph = ((kk * 4 + quad) ^ (lane & 7)) << 4;
    bf16x8 a[2], b[2];
#pragma unroll
    for (int rh = 0; rh < 2; ++rh)
      a[rh] = *(const bf16x8*)(h1s + (rh * 16 + lane16) * 256 + ph);
#pragma unroll
    for (int nt = 0; nt < 2; ++nt)
      b[nt] = *(const bf16x8*)(w2t + (size_t)(n_base + nt * 16 + lane16) * 128 +
                               kk * 32 + quad * 8);
#pragma unroll
    for (int rh = 0; rh < 2; ++rh)
#pragma unroll
      for (int nt = 0; nt < 2; ++nt)
        acc2[rh][nt] = __builtin_amdgcn_mfma_f32_16x16x32_bf16(
            a[rh], b[nt], acc2[rh][nt], 0, 0, 0);
  }
#pragma unroll
  for (int rh = 0; rh < 2; ++rh)
#pragma unroll
    for (int nt = 0; nt < 2; ++nt) {
      int col = n_base + nt * 16 + lane16;
#pragma unroll
      for (int r = 0; r < 4; ++r) {
        int row = rh * 16 + quad * 4 + r;
        float h1v = bf2f(*(const u16*)(h1s + hoff(row, col)));
        float v = acc2[rh][nt][r] + b2v[nt];
        float res = h1v + fmaxf(v, 0.f);
        outv[(size_t)(row0 + row) * 128 + col] = res;
      }
    }
}

// ---------------------------------------------------------------------------
extern "C" void kernel_launch(void* const* d_in, const int* in_sizes, int n_in,
                              void* d_out, int out_size, void* d_ws, size_t ws_size,
                              hipStream_t stream) {
  const float* x  = (const float*)d_in[0];
  const float* W0 = (const float*)d_in[1];
  const float* b0 = (const float*)d_in[2];
  const float* W1 = (const float*)d_in[3];
  const float* b1 = (const float*)d_in[4];
  const float* W2 = (const float*)d_in[5];
  const float* b2 = (const float*)d_in[6];
  char* wsb = (char*)d_ws;

  prep_kernel<<<161, 256, 0, stream>>>(W0, W1, W2, b0, b1, b2, wsb);
  fused_kernel<<<1024, 256, 0, stream>>>(x, wsb, (float*)d_out);
}